// Round 11
// baseline (420.636 us; speedup 1.0000x reference)
//
#include <hip/hip_runtime.h>

#define B_ 8
#define C_ 129
#define P_ 62
#define L_ 20
#define D_ 256
#define NSEG (B_*C_*P_)   /* 63984 */
#define N2   (B_*P_)      /* 496 */
#define SEGB 4
#define NWG  (NSEG/SEGB)  /* 15996 */

#define S1 1424   /* h1T per-seg stride in u16: 22*64+16 (16 mod 64) */
#define S2 1808   /* hpT per-seg stride in u16: 14*128+16 */

#define FT_STRIDE 168   /* fT [256 d][168] u16 */
#define MT_STRIDE 264   /* mT [144 o][264] u16 */

typedef short short8 __attribute__((ext_vector_type(8)));
typedef float f32x4  __attribute__((ext_vector_type(4)));

// Branchless erf-GELU via A&S 7.1.26 3-term (max |erf err| 2.5e-5) — r8-proven.
__device__ __forceinline__ float gelu_f(float x) {
    float u   = 0.70710678f * x;
    float au  = __builtin_fabsf(u);
    float den = fmaf(0.47047f, au, 1.0f);
    float t   = __builtin_amdgcn_rcpf(den);
    float q   = fmaf(0.7478556f, t, -0.0958798f);
    q = fmaf(q, t, 0.3480242f);
    float P  = q * t;
    float z  = (-1.4426950409f * au) * au;
    float e  = __builtin_amdgcn_exp2f(z);
    float ea = fmaf(-P, e, 1.0f);
    float er = copysignf(ea, x);
    float hx = 0.5f * x;
    return fmaf(hx, er, hx);
}
__device__ __forceinline__ unsigned short f2bf(float f) {
    unsigned u = __float_as_uint(f);
    u = u + 0x7FFFu + ((u >> 16) & 1u);
    return (unsigned short)(u >> 16);
}
__device__ __forceinline__ unsigned cvt_pk_bf16(float lo, float hi) {
    unsigned r;
    asm("v_cvt_pk_bf16_f32 %0, %1, %2" : "=v"(r) : "v"(lo), "v"(hi));
    return r;
}

// ---------------- prep: pack all weights into MFMA fragment order ----------------
__global__ void prep_kernel(const float* __restrict__ w2, const float* __restrict__ w3,
                            const float* __restrict__ mw, const float* __restrict__ pw,
                            const float* __restrict__ mixb, const float* __restrict__ lnw,
                            const float* __restrict__ lnb,
                            unsigned short* __restrict__ A2p, unsigned short* __restrict__ A3p,
                            unsigned short* __restrict__ mixA, unsigned short* __restrict__ projA,
                            float* __restrict__ bmixp, float* __restrict__ lnwp,
                            float* __restrict__ lnbp) {
    int idx = blockIdx.x * blockDim.x + threadIdx.x;
    int stride = gridDim.x * blockDim.x;
    for (int f = idx; f < 6*8*64*8; f += stride) {
        int j = f & 7, ln = (f >> 3) & 63, mt = (f >> 9) & 7, kt = f >> 12;
        int co = mt*16 + (ln & 15);
        int k  = kt >> 1;
        int ci = (kt & 1)*32 + (ln >> 4)*8 + j;
        A2p[f] = f2bf(w2[(co*64 + ci)*3 + k]);
    }
    for (int f = idx; f < 12*16*64*8; f += stride) {
        int j = f & 7, ln = (f >> 3) & 63, mt = (f >> 9) & 15, kt = f >> 13;
        int co = mt*16 + (ln & 15);
        int k  = kt >> 2;
        int ci = (kt & 3)*32 + (ln >> 4)*8 + j;
        A3p[f] = f2bf(w3[(co*128 + ci)*3 + k]);
    }
    for (int f = idx; f < 5*9*64*8; f += stride) {
        int j = f & 7, ln = (f >> 3) & 63;
        int mt = (f >> 9) % 9, kt = (f >> 9) / 9;
        int o = mt*16 + (ln & 15);
        int c = kt*32 + (ln >> 4)*8 + j;
        mixA[f] = (o < 129 && c < 129) ? f2bf(mw[o*129 + c]) : (unsigned short)0;
    }
    for (int f = idx; f < 8*16*64*8; f += stride) {
        int j = f & 7, ln = (f >> 3) & 63, mt = (f >> 9) & 15, kt = f >> 13;
        int e = mt*16 + (ln & 15);
        int d = kt*32 + (ln >> 4)*8 + j;
        projA[f] = f2bf(pw[e*256 + d]);
    }
    for (int i = idx; i < 144; i += stride) {
        bmixp[i] = (i < 129) ? mixb[i] : 0.f;
        lnwp[i]  = (i < 129) ? lnw[i]  : 0.f;
        lnbp[i]  = (i < 129) ? lnb[i]  : 0.f;
    }
}

// ---------------- kernel 1: conv stack via MFMA, SEGB=4 (target 4 blocks/CU) ----------------
// N interleave: n = pos*4 + seg. Lane: seg4 = sL&3, p0 = sL>>2.
__global__ __launch_bounds__(512, 4) void conv_mfma_kernel(
    const float* __restrict__ x,
    const float* __restrict__ w1, const float* __restrict__ b1,
    const unsigned short* __restrict__ A2p, const float* __restrict__ b2,
    const unsigned short* __restrict__ A3p, const float* __restrict__ b3,
    unsigned short* __restrict__ feat)
{
    __shared__ __align__(16) unsigned short h1T[SEGB * S1]; // 11392 B; rows 0,21 zero
    __shared__ __align__(16) unsigned short hpT[SEGB * S2]; // 14464 B; rows 0,11,12,13 zero
    __shared__ float xs[SEGB][22];                          //   352 B

    const int t = threadIdx.x;
    const int wave = t >> 6, lane = t & 63;
    const int sL = lane & 15, gL = lane >> 4;
    const int seg4 = sL & 3, p0 = sL >> 2;
    const int seg0 = blockIdx.x * SEGB;

    if (t < SEGB*22) {
        int s = t / 22, i = t % 22;
        float v = 0.f;
        if (i >= 1 && i <= 20) v = x[(seg0 + s)*L_ + i - 1];
        xs[s][i] = v;
    }
    if (t < SEGB*64) {
        int s = t >> 6, ci = t & 63;
        h1T[s*S1 + ci] = 0;
        h1T[s*S1 + 21*64 + ci] = 0;
    }
    for (int idx = t; idx < SEGB*4*128; idx += 512) {
        int s = idx >> 9;
        int r2 = (idx >> 7) & 3;
        int row = (r2 == 0) ? 0 : 10 + r2;   // rows 0, 11, 12, 13
        int co = idx & 127;
        hpT[s*S2 + row*128 + co] = 0;
    }
    __syncthreads();

    // conv1: wave -> (seg = w&3, pos-half = w>>2); lane -> (chpair, pos-quarter)
    {
        int seg = wave & 3, phh = wave >> 2;
        int cp = lane & 31, pq = lane >> 5;
        int ci0 = cp * 2;
        int l0 = phh*10 + pq*5;
        float wa0 = w1[ci0*3+0], wa1 = w1[ci0*3+1], wa2 = w1[ci0*3+2], ba = b1[ci0];
        float wb0 = w1[ci0*3+3], wb1 = w1[ci0*3+4], wb2 = w1[ci0*3+5], bb = b1[ci0+1];
        unsigned short* dst = &h1T[seg*S1 + ci0];
        #pragma unroll
        for (int i = 0; i < 5; ++i) {
            int l = l0 + i;
            float x0 = xs[seg][l], x1 = xs[seg][l+1], x2v = xs[seg][l+2];
            float va = fmaf(x0, wa0, fmaf(x1, wa1, fmaf(x2v, wa2, ba)));
            float vb = fmaf(x0, wb0, fmaf(x1, wb1, fmaf(x2v, wb2, bb)));
            *(unsigned*)(dst + (l+1)*64) = cvt_pk_bf16(gelu_f(va), gelu_f(vb));
        }
    }
    __syncthreads();

    // conv2 GEMM: M=128 (wave = M-tile), N=80 (5 tiles), K=192.
    // Lane row for tile t: pos = 4t + p0; LDS rows pos+k.
    {
        f32x4 acc[5];
        {
            float4 bb = *(const float4*)(b2 + wave*16 + gL*4);
            f32x4 bi = (f32x4){bb.x, bb.y, bb.z, bb.w};
            #pragma unroll
            for (int n = 0; n < 5; ++n) acc[n] = bi;
        }
        const unsigned short* h1b = &h1T[seg4*S1 + p0*64 + gL*8];
        #pragma unroll
        for (int h = 0; h < 2; ++h) {
            short8 a0 = *(const short8*)(A2p + ((((0*2+h)*8 + wave)*64 + lane) << 3));
            short8 a1 = *(const short8*)(A2p + ((((1*2+h)*8 + wave)*64 + lane) << 3));
            short8 a2 = *(const short8*)(A2p + ((((2*2+h)*8 + wave)*64 + lane) << 3));
            #pragma unroll
            for (int tt = 0; tt < 5; ++tt) {
                const unsigned short* rb = h1b + (4*tt)*64 + h*32;
                short8 b0 = *(const short8*)(rb);
                short8 b1 = *(const short8*)(rb + 64);
                short8 b2v = *(const short8*)(rb + 128);
                acc[tt] = __builtin_amdgcn_mfma_f32_16x16x32_bf16(a0, b0, acc[tt], 0, 0, 0);
                acc[tt] = __builtin_amdgcn_mfma_f32_16x16x32_bf16(a1, b1, acc[tt], 0, 0, 0);
                acc[tt] = __builtin_amdgcn_mfma_f32_16x16x32_bf16(a2, b2v, acc[tt], 0, 0, 0);
            }
        }
        // epilogue: gelu both parities, pool via shfl_xor(4), even-p0 lanes store
        int co0 = wave*16 + gL*4;
        #pragma unroll
        for (int tt = 0; tt < 5; ++tt) {
            float pv[4];
            #pragma unroll
            for (int r = 0; r < 4; ++r) {
                float g = gelu_f(acc[tt][r]);
                pv[r] = fmaxf(g, __shfl_xor(g, 4));
            }
            if ((p0 & 1) == 0) {
                int lp = 2*tt + (p0 >> 1);
                uint2 pk;
                pk.x = cvt_pk_bf16(pv[0], pv[1]);
                pk.y = cvt_pk_bf16(pv[2], pv[3]);
                *(uint2*)&hpT[seg4*S2 + (lp+1)*128 + co0] = pk;
            }
        }
    }
    __syncthreads();

    // conv3 GEMM: M=256 (wave -> 2 M-tiles), N=48 (3 tiles, cols >= 40 masked), K=384.
    {
        f32x4 acc[2][3];
        #pragma unroll
        for (int mi = 0; mi < 2; ++mi) {
            float4 bv = *(const float4*)(b3 + (wave*2 + mi)*16 + gL*4);
            f32x4 bi = (f32x4){bv.x, bv.y, bv.z, bv.w};
            #pragma unroll
            for (int n = 0; n < 3; ++n) acc[mi][n] = bi;
        }
        const unsigned short* hpb = &hpT[seg4*S2 + p0*128 + gL*8];
        #pragma unroll
        for (int q = 0; q < 4; ++q) {
            short8 a[3][2];
            #pragma unroll
            for (int k = 0; k < 3; ++k)
                #pragma unroll
                for (int mi = 0; mi < 2; ++mi)
                    a[k][mi] = *(const short8*)(A3p + ((((k*4+q)*16 + wave*2 + mi)*64 + lane) << 3));
            #pragma unroll
            for (int tt = 0; tt < 3; ++tt) {
                const unsigned short* rb = hpb + (4*tt)*128 + q*32;
                short8 b0 = *(const short8*)(rb);
                short8 b1 = *(const short8*)(rb + 128);
                short8 b2v = *(const short8*)(rb + 256);
                #pragma unroll
                for (int mi = 0; mi < 2; ++mi) {
                    acc[mi][tt] = __builtin_amdgcn_mfma_f32_16x16x32_bf16(a[0][mi], b0, acc[mi][tt], 0, 0, 0);
                    acc[mi][tt] = __builtin_amdgcn_mfma_f32_16x16x32_bf16(a[1][mi], b1, acc[mi][tt], 0, 0, 0);
                    acc[mi][tt] = __builtin_amdgcn_mfma_f32_16x16x32_bf16(a[2][mi], b2v, acc[mi][tt], 0, 0, 0);
                }
            }
        }
        // epilogue: gelu, mask invalid (tile2, p0>=2), in-lane + cross-lane mean
        int seg = seg0 + seg4;
        int bI = seg / (C_*P_);
        int rem = seg % (C_*P_);
        int c = rem / P_, p = rem % P_;
        unsigned short* frow = feat + (((size_t)(bI*P_ + p)*C_ + c) << 8);
        float msk2 = (p0 < 2) ? 1.f : 0.f;
        #pragma unroll
        for (int mi = 0; mi < 2; ++mi) {
            float sum[4] = {0.f, 0.f, 0.f, 0.f};
            #pragma unroll
            for (int tt = 0; tt < 3; ++tt) {
                float m = (tt == 2) ? msk2 : 1.f;
                #pragma unroll
                for (int r = 0; r < 4; ++r)
                    sum[r] = fmaf(gelu_f(acc[mi][tt][r]), m, sum[r]);
            }
            #pragma unroll
            for (int r = 0; r < 4; ++r) {
                sum[r] += __shfl_xor(sum[r], 4);
                sum[r] += __shfl_xor(sum[r], 8);
            }
            if (p0 == 0) {
                int co0 = (wave*2 + mi)*16 + gL*4;
                uint2 o;
                o.x = cvt_pk_bf16(sum[0]*0.1f, sum[1]*0.1f);
                o.y = cvt_pk_bf16(sum[2]*0.1f, sum[3]*0.1f);
                *(uint2*)(frow + co0) = o;
            }
        }
    }
}

// ---------------- kernel 2: fused mix + gelu + LN + proj (MFMA) ----------------
__global__ __launch_bounds__(512, 2) void mix_proj_kernel(
    const unsigned short* __restrict__ feat,
    const unsigned short* __restrict__ mixA, const float* __restrict__ bmixp,
    const float* __restrict__ lnwp, const float* __restrict__ lnbp,
    const unsigned short* __restrict__ projA, const float* __restrict__ proj_b,
    float* __restrict__ out)
{
    __shared__ __align__(16) unsigned short ulds[256*FT_STRIDE];
    unsigned short* fT = ulds;
    unsigned short* mT = ulds;

    const int t = threadIdx.x;
    const int wave = t >> 6, lane = t & 63;
    const int sL = lane & 15, gL = lane >> 4;
    const int n2 = blockIdx.x;
    const int b = n2 / P_, p = n2 % P_;

    const unsigned* fbase32 = (const unsigned*)(feat + (size_t)n2 * C_ * 256);
    for (int idx = t; idx < 129*128; idx += 512) {
        int c = idx >> 7, q = idx & 127;
        unsigned v = fbase32[idx];
        int d0 = q * 2;
        fT[d0*FT_STRIDE + c]     = (unsigned short)(v & 0xFFFFu);
        fT[(d0+1)*FT_STRIDE + c] = (unsigned short)(v >> 16);
    }
    for (int idx = t; idx < 256*31; idx += 512) {
        int d = idx / 31, c = 129 + idx % 31;
        fT[d*FT_STRIDE + c] = 0;
    }
    __syncthreads();

    f32x4 acc[9][2];
    #pragma unroll
    for (int mt = 0; mt < 9; ++mt) {
        float4 bv = *(const float4*)(bmixp + mt*16 + gL*4);
        f32x4 bi = (f32x4){bv.x, bv.y, bv.z, bv.w};
        acc[mt][0] = bi;
        acc[mt][1] = bi;
    }

    #pragma unroll
    for (int kt = 0; kt < 5; ++kt) {
        short8 bb[2];
        #pragma unroll
        for (int nt = 0; nt < 2; ++nt) {
            int d = (wave*2 + nt)*16 + sL;
            bb[nt] = *(const short8*)&fT[d*FT_STRIDE + kt*32 + gL*8];
        }
        #pragma unroll
        for (int mt = 0; mt < 9; ++mt) {
            short8 a = *(const short8*)(mixA + (((kt*9 + mt)*64 + lane) << 3));
            #pragma unroll
            for (int nt = 0; nt < 2; ++nt)
                acc[mt][nt] = __builtin_amdgcn_mfma_f32_16x16x32_bf16(a, bb[nt], acc[mt][nt], 0, 0, 0);
        }
    }

    float sum[2] = {0.f, 0.f}, sq[2] = {0.f, 0.f};
    #pragma unroll
    for (int mt = 0; mt < 9; ++mt) {
        #pragma unroll
        for (int nt = 0; nt < 2; ++nt) {
            #pragma unroll
            for (int r = 0; r < 4; ++r) {
                float g = gelu_f(acc[mt][nt][r]);
                acc[mt][nt][r] = g;
                sum[nt] += g;
                sq[nt]  += g*g;
            }
        }
    }
    float mu[2], rs[2];
    #pragma unroll
    for (int nt = 0; nt < 2; ++nt) {
        float s = sum[nt], q = sq[nt];
        s += __shfl_xor(s, 16); q += __shfl_xor(q, 16);
        s += __shfl_xor(s, 32); q += __shfl_xor(q, 32);
        mu[nt] = s * (1.f/129.f);
        float var = q * (1.f/129.f) - mu[nt]*mu[nt];
        rs[nt] = rsqrtf(var + 1e-5f);
    }

    __syncthreads();

    #pragma unroll
    for (int mt = 0; mt < 9; ++mt) {
        float4 lw = *(const float4*)(lnwp + mt*16 + gL*4);
        float4 lb = *(const float4*)(lnbp + mt*16 + gL*4);
        float lwr[4] = {lw.x, lw.y, lw.z, lw.w};
        float lbr[4] = {lb.x, lb.y, lb.z, lb.w};
        #pragma unroll
        for (int nt = 0; nt < 2; ++nt) {
            int d = (wave*2 + nt)*16 + sL;
            #pragma unroll
            for (int r = 0; r < 4; ++r) {
                int o = mt*16 + gL*4 + r;
                float y = (acc[mt][nt][r] - mu[nt]) * rs[nt] * lwr[r] + lbr[r];
                mT[o*MT_STRIDE + d] = f2bf(y);
            }
        }
    }
    __syncthreads();

    f32x4 pacc[2][9];
    #pragma unroll
    for (int mi = 0; mi < 2; ++mi)
        #pragma unroll
        for (int nt = 0; nt < 9; ++nt) pacc[mi][nt] = (f32x4){0.f,0.f,0.f,0.f};

    #pragma unroll
    for (int kt = 0; kt < 8; ++kt) {
        short8 a[2];
        #pragma unroll
        for (int mi = 0; mi < 2; ++mi)
            a[mi] = *(const short8*)(projA + (((kt*16 + wave*2 + mi)*64 + lane) << 3));
        #pragma unroll
        for (int nt = 0; nt < 9; ++nt) {
            short8 bb = *(const short8*)&mT[(nt*16 + sL)*MT_STRIDE + kt*32 + gL*8];
            #pragma unroll
            for (int mi = 0; mi < 2; ++mi)
                pacc[mi][nt] = __builtin_amdgcn_mfma_f32_16x16x32_bf16(a[mi], bb, pacc[mi][nt], 0, 0, 0);
        }
    }

    #pragma unroll
    for (int mi = 0; mi < 2; ++mi) {
        int e0 = (wave*2 + mi)*16 + gL*4;
        float4 pb4 = *(const float4*)(proj_b + e0);
        #pragma unroll
        for (int nt = 0; nt < 9; ++nt) {
            int c = nt*16 + sL;
            if (c < 129) {
                float4 o4;
                o4.x = pacc[mi][nt][0] + pb4.x;
                o4.y = pacc[mi][nt][1] + pb4.y;
                o4.z = pacc[mi][nt][2] + pb4.z;
                o4.w = pacc[mi][nt][3] + pb4.w;
                *(float4*)&out[(((size_t)(b*C_ + c)*P_) + p)*256 + e0] = o4;
            }
        }
    }
}

extern "C" void kernel_launch(void* const* d_in, const int* in_sizes, int n_in,
                              void* d_out, int out_size, void* d_ws, size_t ws_size,
                              hipStream_t stream) {
    (void)in_sizes; (void)n_in; (void)out_size; (void)ws_size;
    const float* x    = (const float*)d_in[0];
    const float* w1   = (const float*)d_in[1];
    const float* b1   = (const float*)d_in[2];
    const float* w2   = (const float*)d_in[3];
    const float* b2   = (const float*)d_in[4];
    const float* w3   = (const float*)d_in[5];
    const float* b3   = (const float*)d_in[6];
    const float* mixw = (const float*)d_in[7];
    const float* mixb = (const float*)d_in[8];
    const float* lnw  = (const float*)d_in[9];
    const float* lnb  = (const float*)d_in[10];
    const float* pw   = (const float*)d_in[11];
    const float* pb   = (const float*)d_in[12];
    float* out = (float*)d_out;
    float* ws  = (float*)d_ws;

    unsigned short* feat = (unsigned short*)ws;              // 63984*256 bf16 (32.7 MB)
    unsigned short* A2p  = (unsigned short*)(ws + 16379904); // 24576 u16
    unsigned short* A3p  = A2p + 24576;                      // 98304 u16
    unsigned short* mixA = A3p + 98304;                      // 23040 u16
    unsigned short* projA = mixA + 23040;                    // 65536 u16
    float* bmixp = (float*)(projA + 65536);                  // 144
    float* lnwp  = bmixp + 144;                              // 144
    float* lnbp  = lnwp + 144;                               // 144

    prep_kernel<<<256, 256, 0, stream>>>(w2, w3, mixw, pw, mixb, lnw, lnb,
                                         A2p, A3p, mixA, projA, bmixp, lnwp, lnbp);
    conv_mfma_kernel<<<NWG, 512, 0, stream>>>(x, w1, b1, A2p, b2, A3p, b3, feat);
    mix_proj_kernel<<<N2, 512, 0, stream>>>(feat, mixA, bmixp, lnwp, lnbp, projA, pb, out);
}

// Round 12
// 359.637 us; speedup vs baseline: 1.1696x; 1.1696x over previous
//
#include <hip/hip_runtime.h>

#define B_ 8
#define C_ 129
#define P_ 62
#define L_ 20
#define D_ 256
#define NSEG (B_*C_*P_)   /* 63984 */
#define N2   (B_*P_)      /* 496 */
#define SEGB 8
#define NWG  (NSEG/SEGB)  /* 7998 */

#define S1 1416   /* h1T per-seg stride in u16 */
#define S2 1544   /* hpT per-seg stride in u16 */

#define FT_STRIDE 168   /* fT [256 d][168] u16 */
#define MT_STRIDE 264   /* mT [144 o][264] u16 */

typedef short short8 __attribute__((ext_vector_type(8)));
typedef float f32x4  __attribute__((ext_vector_type(4)));

// erf-GELU via A&S 7.1.26 3-term (|erf err| <= 2.5e-5), algebraically reduced:
//   gelu(x) = relu(x) - 0.5*|x| * P(t) * exp2(-log2e * u^2),  u = |x|/sqrt2
// (0.5x + 0.5|x| = relu(x) removes copysign + 1 mul vs round-8 form)
__device__ __forceinline__ float gelu_f(float x) {
    float ax  = __builtin_fabsf(x);
    float au  = 0.70710678f * ax;
    float den = fmaf(0.47047f, au, 1.0f);
    float t   = __builtin_amdgcn_rcpf(den);
    float q   = fmaf(0.7478556f, t, -0.0958798f);
    q = fmaf(q, t, 0.3480242f);
    float P  = q * t;
    float z  = au * (-1.4426950409f * au);
    float e  = __builtin_amdgcn_exp2f(z);
    float t2 = ax * (P * e);
    return fmaf(t2, -0.5f, fmaxf(x, 0.f));
}
__device__ __forceinline__ unsigned short f2bf(float f) {   // scalar RNE (prep / mT only)
    unsigned u = __float_as_uint(f);
    u = u + 0x7FFFu + ((u >> 16) & 1u);
    return (unsigned short)(u >> 16);
}
// HW packed f32->bf16 RNE conversion (proven rounds 7-11)
__device__ __forceinline__ unsigned cvt_pk_bf16(float lo, float hi) {
    unsigned r;
    asm("v_cvt_pk_bf16_f32 %0, %1, %2" : "=v"(r) : "v"(lo), "v"(hi));
    return r;
}

// ---------------- prep: pack all weights into MFMA fragment order ----------------
__global__ void prep_kernel(const float* __restrict__ w2, const float* __restrict__ w3,
                            const float* __restrict__ mw, const float* __restrict__ pw,
                            const float* __restrict__ mixb, const float* __restrict__ lnw,
                            const float* __restrict__ lnb,
                            unsigned short* __restrict__ A2p, unsigned short* __restrict__ A3p,
                            unsigned short* __restrict__ mixA, unsigned short* __restrict__ projA,
                            float* __restrict__ bmixp, float* __restrict__ lnwp,
                            float* __restrict__ lnbp) {
    int idx = blockIdx.x * blockDim.x + threadIdx.x;
    int stride = gridDim.x * blockDim.x;
    for (int f = idx; f < 6*8*64*8; f += stride) {
        int j = f & 7, ln = (f >> 3) & 63, mt = (f >> 9) & 7, kt = f >> 12;
        int co = mt*16 + (ln & 15);
        int k  = kt >> 1;
        int ci = (kt & 1)*32 + (ln >> 4)*8 + j;
        A2p[f] = f2bf(w2[(co*64 + ci)*3 + k]);
    }
    for (int f = idx; f < 12*16*64*8; f += stride) {
        int j = f & 7, ln = (f >> 3) & 63, mt = (f >> 9) & 15, kt = f >> 13;
        int co = mt*16 + (ln & 15);
        int k  = kt >> 2;
        int ci = (kt & 3)*32 + (ln >> 4)*8 + j;
        A3p[f] = f2bf(w3[(co*128 + ci)*3 + k]);
    }
    for (int f = idx; f < 5*9*64*8; f += stride) {
        int j = f & 7, ln = (f >> 3) & 63;
        int mt = (f >> 9) % 9, kt = (f >> 9) / 9;
        int o = mt*16 + (ln & 15);
        int c = kt*32 + (ln >> 4)*8 + j;
        mixA[f] = (o < 129 && c < 129) ? f2bf(mw[o*129 + c]) : (unsigned short)0;
    }
    for (int f = idx; f < 8*16*64*8; f += stride) {
        int j = f & 7, ln = (f >> 3) & 63, mt = (f >> 9) & 15, kt = f >> 13;
        int e = mt*16 + (ln & 15);
        int d = kt*32 + (ln >> 4)*8 + j;
        projA[f] = f2bf(pw[e*256 + d]);
    }
    for (int i = idx; i < 144; i += stride) {
        bmixp[i] = (i < 129) ? mixb[i] : 0.f;
        lnwp[i]  = (i < 129) ? lnw[i]  : 0.f;
        lnbp[i]  = (i < 129) ? lnb[i]  : 0.f;
    }
}

// ---------------- kernel 1: conv stack via MFMA, SEGB=8 (round-8 structure) ----------------
__global__ __launch_bounds__(512, 2) void conv_mfma_kernel(
    const float* __restrict__ x,
    const float* __restrict__ w1, const float* __restrict__ b1,
    const unsigned short* __restrict__ A2p, const float* __restrict__ b2,
    const unsigned short* __restrict__ A3p, const float* __restrict__ b3,
    unsigned short* __restrict__ feat)
{
    __shared__ __align__(16) unsigned short h1T[SEGB * S1]; // 22656 B
    __shared__ __align__(16) unsigned short hpT[SEGB * S2]; // 24704 B
    __shared__ float xs[SEGB][22];                          //   704 B

    const int t = threadIdx.x;
    const int wave = t >> 6, lane = t & 63;
    const int sL = lane & 15, gL = lane >> 4;
    const int seg8 = sL & 7, hi8 = sL >> 3;
    const int seg0 = blockIdx.x * SEGB;

    for (int idx = t; idx < SEGB*22; idx += 512) {
        int s = idx / 22, i = idx % 22;
        float v = 0.f;
        if (i >= 1 && i <= 20) v = x[(seg0 + s)*L_ + i - 1];
        xs[s][i] = v;
    }
    for (int idx = t; idx < SEGB*64; idx += 512) {
        int s = idx >> 6, ci = idx & 63;
        h1T[s*S1 + ci] = 0;
        h1T[s*S1 + 21*64 + ci] = 0;
    }
    for (int idx = t; idx < SEGB*128; idx += 512) {
        int s = idx >> 7, co = idx & 127;
        hpT[s*S2 + co] = 0;
        hpT[s*S2 + 11*128 + co] = 0;
    }
    __syncthreads();

    // conv1: wave w owns seg w; paired channels; cvt_pk + b32 writes
    {
        int seg = wave;
        int cp = (lane >> 1) & 31, ph = lane & 1;
        int ci0 = cp * 2;
        float wa0 = w1[ci0*3+0], wa1 = w1[ci0*3+1], wa2 = w1[ci0*3+2], ba = b1[ci0];
        float wb0 = w1[ci0*3+3], wb1 = w1[ci0*3+4], wb2 = w1[ci0*3+5], bb = b1[ci0+1];
        unsigned short* dst = &h1T[seg*S1 + ci0];
        #pragma unroll
        for (int i = 0; i < 10; ++i) {
            int l = ph*10 + i;
            float x0 = xs[seg][l], x1 = xs[seg][l+1], x2v = xs[seg][l+2];
            float va = fmaf(x0, wa0, fmaf(x1, wa1, fmaf(x2v, wa2, ba)));
            float vb = fmaf(x0, wb0, fmaf(x1, wb1, fmaf(x2v, wb2, bb)));
            *(unsigned*)(dst + (l+1)*64) = cvt_pk_bf16(gelu_f(va), gelu_f(vb));
        }
    }
    __syncthreads();

    // conv2 GEMM: M=128, N=160, K=192; bias preloaded into accumulators
    {
        const int mh = wave & 3, ng = wave >> 2;
        f32x4 bias[2];
        #pragma unroll
        for (int mi = 0; mi < 2; ++mi) {
            float4 bb = *(const float4*)(b2 + (mh*2 + mi)*16 + gL*4);
            bias[mi] = (f32x4){bb.x, bb.y, bb.z, bb.w};
        }
        f32x4 acc[2][5];
        #pragma unroll
        for (int mi = 0; mi < 2; ++mi)
            #pragma unroll
            for (int n = 0; n < 5; ++n) acc[mi][n] = bias[mi];

        const unsigned short* h1base = &h1T[seg8*S1 + (ng*10 + hi8)*64 + gL*8];
        #pragma unroll
        for (int h = 0; h < 2; ++h) {
            short8 br[11];
            #pragma unroll
            for (int r = 0; r < 11; ++r)
                br[r] = *(const short8*)(h1base + r*64 + h*32);
            #pragma unroll
            for (int k = 0; k < 3; ++k) {
                int kt = k*2 + h;
                short8 a0 = *(const short8*)(A2p + (((kt*8 + mh*2 + 0)*64 + lane) << 3));
                short8 a1 = *(const short8*)(A2p + (((kt*8 + mh*2 + 1)*64 + lane) << 3));
                #pragma unroll
                for (int n = 0; n < 5; ++n) {
                    acc[0][n] = __builtin_amdgcn_mfma_f32_16x16x32_bf16(a0, br[2*n+k], acc[0][n], 0, 0, 0);
                    acc[1][n] = __builtin_amdgcn_mfma_f32_16x16x32_bf16(a1, br[2*n+k], acc[1][n], 0, 0, 0);
                }
            }
        }
        #pragma unroll
        for (int mi = 0; mi < 2; ++mi) {
            int mt = mh*2 + mi;
            int co0 = mt*16 + gL*4;
            #pragma unroll
            for (int n = 0; n < 5; ++n) {
                int lp = ng*5 + n;
                float pv[4];
                #pragma unroll
                for (int r = 0; r < 4; ++r) {
                    float g = gelu_f(acc[mi][n][r]);
                    pv[r] = fmaxf(g, __shfl_xor(g, 8));
                }
                if (hi8 == 0) {
                    uint2 pk;
                    pk.x = cvt_pk_bf16(pv[0], pv[1]);
                    pk.y = cvt_pk_bf16(pv[2], pv[3]);
                    *(uint2*)&hpT[seg8*S2 + (lp+1)*128 + co0] = pk;
                }
            }
        }
    }
    __syncthreads();

    // conv3 GEMM: M=256, N=80, K=384; bias in acc; gelu + mean; bf16 feat output
    {
        f32x4 bias[2];
        #pragma unroll
        for (int mi = 0; mi < 2; ++mi) {
            float4 bv = *(const float4*)(b3 + (wave*2 + mi)*16 + gL*4);
            bias[mi] = (f32x4){bv.x, bv.y, bv.z, bv.w};
        }
        f32x4 acc[2][5];
        #pragma unroll
        for (int mi = 0; mi < 2; ++mi)
            #pragma unroll
            for (int n = 0; n < 5; ++n) acc[mi][n] = bias[mi];

        const unsigned short* hpbase = &hpT[seg8*S2 + hi8*128 + gL*8];
        #pragma unroll
        for (int q = 0; q < 4; ++q) {
            short8 br[11];
            #pragma unroll
            for (int r = 0; r < 11; ++r)
                br[r] = *(const short8*)(hpbase + r*128 + q*32);
            #pragma unroll
            for (int k = 0; k < 3; ++k) {
                int kt = k*4 + q;
                short8 a0 = *(const short8*)(A3p + (((kt*16 + wave*2 + 0)*64 + lane) << 3));
                short8 a1 = *(const short8*)(A3p + (((kt*16 + wave*2 + 1)*64 + lane) << 3));
                #pragma unroll
                for (int n = 0; n < 5; ++n) {
                    acc[0][n] = __builtin_amdgcn_mfma_f32_16x16x32_bf16(a0, br[2*n+k], acc[0][n], 0, 0, 0);
                    acc[1][n] = __builtin_amdgcn_mfma_f32_16x16x32_bf16(a1, br[2*n+k], acc[1][n], 0, 0, 0);
                }
            }
        }
        int seg = seg0 + seg8;
        int bI = seg / (C_*P_);
        int rem = seg % (C_*P_);
        int c = rem / P_, p = rem % P_;
        unsigned short* frow = feat + (((size_t)(bI*P_ + p)*C_ + c) << 8);
        #pragma unroll
        for (int mi = 0; mi < 2; ++mi) {
            int co0 = (wave*2 + mi)*16 + gL*4;
            float sum[4] = {0.f, 0.f, 0.f, 0.f};
            #pragma unroll
            for (int n = 0; n < 5; ++n)
                #pragma unroll
                for (int r = 0; r < 4; ++r)
                    sum[r] += gelu_f(acc[mi][n][r]);
            #pragma unroll
            for (int r = 0; r < 4; ++r)
                sum[r] += __shfl_xor(sum[r], 8);
            if (hi8 == 0) {
                uint2 o;
                o.x = cvt_pk_bf16(sum[0]*0.1f, sum[1]*0.1f);
                o.y = cvt_pk_bf16(sum[2]*0.1f, sum[3]*0.1f);
                *(uint2*)(frow + co0) = o;
            }
        }
    }
}

// ---------------- kernel 2: fused mix + gelu + LN + proj (MFMA) ----------------
__global__ __launch_bounds__(512, 2) void mix_proj_kernel(
    const unsigned short* __restrict__ feat,
    const unsigned short* __restrict__ mixA, const float* __restrict__ bmixp,
    const float* __restrict__ lnwp, const float* __restrict__ lnbp,
    const unsigned short* __restrict__ projA, const float* __restrict__ proj_b,
    float* __restrict__ out)
{
    __shared__ __align__(16) unsigned short ulds[256*FT_STRIDE];
    unsigned short* fT = ulds;
    unsigned short* mT = ulds;

    const int t = threadIdx.x;
    const int wave = t >> 6, lane = t & 63;
    const int sL = lane & 15, gL = lane >> 4;
    const int n2 = blockIdx.x;
    const int b = n2 / P_, p = n2 % P_;

    // stage fT[d][c] from bf16 feat (pure copy; pairs of d per u32)
    const unsigned* fbase32 = (const unsigned*)(feat + (size_t)n2 * C_ * 256);
    for (int idx = t; idx < 129*128; idx += 512) {
        int c = idx >> 7, q = idx & 127;
        unsigned v = fbase32[idx];
        int d0 = q * 2;
        fT[d0*FT_STRIDE + c]     = (unsigned short)(v & 0xFFFFu);
        fT[(d0+1)*FT_STRIDE + c] = (unsigned short)(v >> 16);
    }
    for (int idx = t; idx < 256*31; idx += 512) {
        int d = idx / 31, c = 129 + idx % 31;
        fT[d*FT_STRIDE + c] = 0;
    }
    __syncthreads();

    // mix GEMM: bias preloaded into accumulators (zero rows for o>=129)
    f32x4 acc[9][2];
    #pragma unroll
    for (int mt = 0; mt < 9; ++mt) {
        float4 bv = *(const float4*)(bmixp + mt*16 + gL*4);
        f32x4 bi = (f32x4){bv.x, bv.y, bv.z, bv.w};
        acc[mt][0] = bi;
        acc[mt][1] = bi;
    }

    #pragma unroll
    for (int kt = 0; kt < 5; ++kt) {
        short8 bb[2];
        #pragma unroll
        for (int nt = 0; nt < 2; ++nt) {
            int d = (wave*2 + nt)*16 + sL;
            bb[nt] = *(const short8*)&fT[d*FT_STRIDE + kt*32 + gL*8];
        }
        #pragma unroll
        for (int mt = 0; mt < 9; ++mt) {
            short8 a = *(const short8*)(mixA + (((kt*9 + mt)*64 + lane) << 3));
            #pragma unroll
            for (int nt = 0; nt < 2; ++nt)
                acc[mt][nt] = __builtin_amdgcn_mfma_f32_16x16x32_bf16(a, bb[nt], acc[mt][nt], 0, 0, 0);
        }
    }

    // gelu + LN stats (acc=0 for o>=129 -> gelu(0)=0 exactly, no mask needed)
    float sum[2] = {0.f, 0.f}, sq[2] = {0.f, 0.f};
    #pragma unroll
    for (int mt = 0; mt < 9; ++mt) {
        #pragma unroll
        for (int nt = 0; nt < 2; ++nt) {
            #pragma unroll
            for (int r = 0; r < 4; ++r) {
                float g = gelu_f(acc[mt][nt][r]);
                acc[mt][nt][r] = g;
                sum[nt] += g;
                sq[nt]  += g*g;
            }
        }
    }
    float mu[2], rs[2];
    #pragma unroll
    for (int nt = 0; nt < 2; ++nt) {
        float s = sum[nt], q = sq[nt];
        s += __shfl_xor(s, 16); q += __shfl_xor(q, 16);
        s += __shfl_xor(s, 32); q += __shfl_xor(q, 32);
        mu[nt] = s * (1.f/129.f);
        float var = q * (1.f/129.f) - mu[nt]*mu[nt];
        rs[nt] = rsqrtf(var + 1e-5f);
    }

    __syncthreads();

    #pragma unroll
    for (int mt = 0; mt < 9; ++mt) {
        float4 lw = *(const float4*)(lnwp + mt*16 + gL*4);
        float4 lb = *(const float4*)(lnbp + mt*16 + gL*4);
        float lwr[4] = {lw.x, lw.y, lw.z, lw.w};
        float lbr[4] = {lb.x, lb.y, lb.z, lb.w};
        #pragma unroll
        for (int nt = 0; nt < 2; ++nt) {
            int d = (wave*2 + nt)*16 + sL;
            #pragma unroll
            for (int r = 0; r < 4; ++r) {
                int o = mt*16 + gL*4 + r;
                float y = (acc[mt][nt][r] - mu[nt]) * rs[nt] * lwr[r] + lbr[r];
                mT[o*MT_STRIDE + d] = f2bf(y);
            }
        }
    }
    __syncthreads();

    f32x4 pacc[2][9];
    #pragma unroll
    for (int mi = 0; mi < 2; ++mi)
        #pragma unroll
        for (int nt = 0; nt < 9; ++nt) pacc[mi][nt] = (f32x4){0.f,0.f,0.f,0.f};

    #pragma unroll
    for (int kt = 0; kt < 8; ++kt) {
        short8 a[2];
        #pragma unroll
        for (int mi = 0; mi < 2; ++mi)
            a[mi] = *(const short8*)(projA + (((kt*16 + wave*2 + mi)*64 + lane) << 3));
        #pragma unroll
        for (int nt = 0; nt < 9; ++nt) {
            short8 bb = *(const short8*)&mT[(nt*16 + sL)*MT_STRIDE + kt*32 + gL*8];
            #pragma unroll
            for (int mi = 0; mi < 2; ++mi)
                pacc[mi][nt] = __builtin_amdgcn_mfma_f32_16x16x32_bf16(a[mi], bb, pacc[mi][nt], 0, 0, 0);
        }
    }

    #pragma unroll
    for (int mi = 0; mi < 2; ++mi) {
        int e0 = (wave*2 + mi)*16 + gL*4;
        float4 pb4 = *(const float4*)(proj_b + e0);
        #pragma unroll
        for (int nt = 0; nt < 9; ++nt) {
            int c = nt*16 + sL;
            if (c < 129) {
                float4 o4;
                o4.x = pacc[mi][nt][0] + pb4.x;
                o4.y = pacc[mi][nt][1] + pb4.y;
                o4.z = pacc[mi][nt][2] + pb4.z;
                o4.w = pacc[mi][nt][3] + pb4.w;
                *(float4*)&out[(((size_t)(b*C_ + c)*P_) + p)*256 + e0] = o4;
            }
        }
    }
}

extern "C" void kernel_launch(void* const* d_in, const int* in_sizes, int n_in,
                              void* d_out, int out_size, void* d_ws, size_t ws_size,
                              hipStream_t stream) {
    (void)in_sizes; (void)n_in; (void)out_size; (void)ws_size;
    const float* x    = (const float*)d_in[0];
    const float* w1   = (const float*)d_in[1];
    const float* b1   = (const float*)d_in[2];
    const float* w2   = (const float*)d_in[3];
    const float* b2   = (const float*)d_in[4];
    const float* w3   = (const float*)d_in[5];
    const float* b3   = (const float*)d_in[6];
    const float* mixw = (const float*)d_in[7];
    const float* mixb = (const float*)d_in[8];
    const float* lnw  = (const float*)d_in[9];
    const float* lnb  = (const float*)d_in[10];
    const float* pw   = (const float*)d_in[11];
    const float* pb   = (const float*)d_in[12];
    float* out = (float*)d_out;
    float* ws  = (float*)d_ws;

    unsigned short* feat = (unsigned short*)ws;              // 63984*256 bf16 (32.7 MB)
    unsigned short* A2p  = (unsigned short*)(ws + 16379904); // 24576 u16
    unsigned short* A3p  = A2p + 24576;                      // 98304 u16
    unsigned short* mixA = A3p + 98304;                      // 23040 u16
    unsigned short* projA = mixA + 23040;                    // 65536 u16
    float* bmixp = (float*)(projA + 65536);                  // 144
    float* lnwp  = bmixp + 144;                              // 144
    float* lnbp  = lnwp + 144;                               // 144

    prep_kernel<<<256, 256, 0, stream>>>(w2, w3, mixw, pw, mixb, lnw, lnb,
                                         A2p, A3p, mixA, projA, bmixp, lnwp, lnbp);
    conv_mfma_kernel<<<NWG, 512, 0, stream>>>(x, w1, b1, A2p, b2, A3p, b3, feat);
    mix_proj_kernel<<<N2, 512, 0, stream>>>(feat, mixA, bmixp, lnwp, lnbp, projA, pb, out);
}

// Round 13
// 352.460 us; speedup vs baseline: 1.1934x; 1.0204x over previous
//
#include <hip/hip_runtime.h>

#define B_ 8
#define C_ 129
#define P_ 62
#define L_ 20
#define D_ 256
#define NSEG (B_*C_*P_)   /* 63984 */
#define N2   (B_*P_)      /* 496 */
#define SEGB 8
#define NWG  (NSEG/SEGB)  /* 7998 */

#define S1 1416   /* h1T per-seg stride in u16 */
#define S2 1544   /* hpT per-seg stride in u16 */

#define FT_STRIDE 168   /* fT [256 d][168] u16 */
#define MT_STRIDE 264   /* mT [144 o][264] u16 */

typedef short short8 __attribute__((ext_vector_type(8)));
typedef float f32x4  __attribute__((ext_vector_type(4)));

// Branchless erf-GELU via Abramowitz-Stegun 7.1.26 3-term (max |erf err| 2.5e-5).
// Best-measured formulation (round 8: 352.2 us total).
__device__ __forceinline__ float gelu_f(float x) {
    float u   = 0.70710678f * x;
    float au  = __builtin_fabsf(u);
    float den = fmaf(0.47047f, au, 1.0f);
    float t   = __builtin_amdgcn_rcpf(den);
    float q   = fmaf(0.7478556f, t, -0.0958798f);
    q = fmaf(q, t, 0.3480242f);
    float P  = q * t;
    float z  = (-1.4426950409f * au) * au;
    float e  = __builtin_amdgcn_exp2f(z);
    float ea = fmaf(-P, e, 1.0f);          // erf(|u|)
    float er = copysignf(ea, x);
    float hx = 0.5f * x;
    return fmaf(hx, er, hx);               // 0.5x(1+erf)
}
__device__ __forceinline__ unsigned short f2bf(float f) {   // scalar RNE (prep / mT only)
    unsigned u = __float_as_uint(f);
    u = u + 0x7FFFu + ((u >> 16) & 1u);
    return (unsigned short)(u >> 16);
}
// HW packed f32->bf16 RNE conversion
__device__ __forceinline__ unsigned cvt_pk_bf16(float lo, float hi) {
    unsigned r;
    asm("v_cvt_pk_bf16_f32 %0, %1, %2" : "=v"(r) : "v"(lo), "v"(hi));
    return r;
}

// ---------------- prep: pack all weights into MFMA fragment order ----------------
__global__ void prep_kernel(const float* __restrict__ w2, const float* __restrict__ w3,
                            const float* __restrict__ mw, const float* __restrict__ pw,
                            const float* __restrict__ mixb, const float* __restrict__ lnw,
                            const float* __restrict__ lnb,
                            unsigned short* __restrict__ A2p, unsigned short* __restrict__ A3p,
                            unsigned short* __restrict__ mixA, unsigned short* __restrict__ projA,
                            float* __restrict__ bmixp, float* __restrict__ lnwp,
                            float* __restrict__ lnbp) {
    int idx = blockIdx.x * blockDim.x + threadIdx.x;
    int stride = gridDim.x * blockDim.x;
    for (int f = idx; f < 6*8*64*8; f += stride) {
        int j = f & 7, ln = (f >> 3) & 63, mt = (f >> 9) & 7, kt = f >> 12;
        int co = mt*16 + (ln & 15);
        int k  = kt >> 1;
        int ci = (kt & 1)*32 + (ln >> 4)*8 + j;
        A2p[f] = f2bf(w2[(co*64 + ci)*3 + k]);
    }
    for (int f = idx; f < 12*16*64*8; f += stride) {
        int j = f & 7, ln = (f >> 3) & 63, mt = (f >> 9) & 15, kt = f >> 13;
        int co = mt*16 + (ln & 15);
        int k  = kt >> 2;
        int ci = (kt & 3)*32 + (ln >> 4)*8 + j;
        A3p[f] = f2bf(w3[(co*128 + ci)*3 + k]);
    }
    for (int f = idx; f < 5*9*64*8; f += stride) {
        int j = f & 7, ln = (f >> 3) & 63;
        int mt = (f >> 9) % 9, kt = (f >> 9) / 9;
        int o = mt*16 + (ln & 15);
        int c = kt*32 + (ln >> 4)*8 + j;
        mixA[f] = (o < 129 && c < 129) ? f2bf(mw[o*129 + c]) : (unsigned short)0;
    }
    for (int f = idx; f < 8*16*64*8; f += stride) {
        int j = f & 7, ln = (f >> 3) & 63, mt = (f >> 9) & 15, kt = f >> 13;
        int e = mt*16 + (ln & 15);
        int d = kt*32 + (ln >> 4)*8 + j;
        projA[f] = f2bf(pw[e*256 + d]);
    }
    for (int i = idx; i < 144; i += stride) {
        bmixp[i] = (i < 129) ? mixb[i] : 0.f;
        lnwp[i]  = (i < 129) ? lnw[i]  : 0.f;
        lnbp[i]  = (i < 129) ? lnb[i]  : 0.f;
    }
}

// ---------------- kernel 1: conv stack via MFMA, SEGB=8 ----------------
__global__ __launch_bounds__(512, 2) void conv_mfma_kernel(
    const float* __restrict__ x,
    const float* __restrict__ w1, const float* __restrict__ b1,
    const unsigned short* __restrict__ A2p, const float* __restrict__ b2,
    const unsigned short* __restrict__ A3p, const float* __restrict__ b3,
    unsigned short* __restrict__ feat)
{
    __shared__ __align__(16) unsigned short h1T[SEGB * S1]; // 22656 B
    __shared__ __align__(16) unsigned short hpT[SEGB * S2]; // 24704 B
    __shared__ float xs[SEGB][22];                          //   704 B

    const int t = threadIdx.x;
    const int wave = t >> 6, lane = t & 63;
    const int sL = lane & 15, gL = lane >> 4;
    const int seg8 = sL & 7, hi8 = sL >> 3;
    const int seg0 = blockIdx.x * SEGB;

    for (int idx = t; idx < SEGB*22; idx += 512) {
        int s = idx / 22, i = idx % 22;
        float v = 0.f;
        if (i >= 1 && i <= 20) v = x[(seg0 + s)*L_ + i - 1];
        xs[s][i] = v;
    }
    for (int idx = t; idx < SEGB*64; idx += 512) {
        int s = idx >> 6, ci = idx & 63;
        h1T[s*S1 + ci] = 0;
        h1T[s*S1 + 21*64 + ci] = 0;
    }
    for (int idx = t; idx < SEGB*128; idx += 512) {
        int s = idx >> 7, co = idx & 127;
        hpT[s*S2 + co] = 0;
        hpT[s*S2 + 11*128 + co] = 0;
    }
    __syncthreads();

    // conv1: wave w owns seg w; paired channels; cvt_pk + b32 writes
    {
        int seg = wave;
        int cp = (lane >> 1) & 31, ph = lane & 1;
        int ci0 = cp * 2;
        float wa0 = w1[ci0*3+0], wa1 = w1[ci0*3+1], wa2 = w1[ci0*3+2], ba = b1[ci0];
        float wb0 = w1[ci0*3+3], wb1 = w1[ci0*3+4], wb2 = w1[ci0*3+5], bb = b1[ci0+1];
        unsigned short* dst = &h1T[seg*S1 + ci0];
        #pragma unroll
        for (int i = 0; i < 10; ++i) {
            int l = ph*10 + i;
            float x0 = xs[seg][l], x1 = xs[seg][l+1], x2v = xs[seg][l+2];
            float va = fmaf(x0, wa0, fmaf(x1, wa1, fmaf(x2v, wa2, ba)));
            float vb = fmaf(x0, wb0, fmaf(x1, wb1, fmaf(x2v, wb2, bb)));
            *(unsigned*)(dst + (l+1)*64) = cvt_pk_bf16(gelu_f(va), gelu_f(vb));
        }
    }
    __syncthreads();

    // conv2 GEMM: M=128, N=160, K=192; bias preloaded into accumulators
    {
        const int mh = wave & 3, ng = wave >> 2;
        f32x4 bias[2];
        #pragma unroll
        for (int mi = 0; mi < 2; ++mi) {
            float4 bb = *(const float4*)(b2 + (mh*2 + mi)*16 + gL*4);
            bias[mi] = (f32x4){bb.x, bb.y, bb.z, bb.w};
        }
        f32x4 acc[2][5];
        #pragma unroll
        for (int mi = 0; mi < 2; ++mi)
            #pragma unroll
            for (int n = 0; n < 5; ++n) acc[mi][n] = bias[mi];

        const unsigned short* h1base = &h1T[seg8*S1 + (ng*10 + hi8)*64 + gL*8];
        #pragma unroll
        for (int h = 0; h < 2; ++h) {
            short8 br[11];
            #pragma unroll
            for (int r = 0; r < 11; ++r)
                br[r] = *(const short8*)(h1base + r*64 + h*32);
            #pragma unroll
            for (int k = 0; k < 3; ++k) {
                int kt = k*2 + h;
                short8 a0 = *(const short8*)(A2p + (((kt*8 + mh*2 + 0)*64 + lane) << 3));
                short8 a1 = *(const short8*)(A2p + (((kt*8 + mh*2 + 1)*64 + lane) << 3));
                #pragma unroll
                for (int n = 0; n < 5; ++n) {
                    acc[0][n] = __builtin_amdgcn_mfma_f32_16x16x32_bf16(a0, br[2*n+k], acc[0][n], 0, 0, 0);
                    acc[1][n] = __builtin_amdgcn_mfma_f32_16x16x32_bf16(a1, br[2*n+k], acc[1][n], 0, 0, 0);
                }
            }
        }
        #pragma unroll
        for (int mi = 0; mi < 2; ++mi) {
            int mt = mh*2 + mi;
            int co0 = mt*16 + gL*4;
            #pragma unroll
            for (int n = 0; n < 5; ++n) {
                int lp = ng*5 + n;
                float pv[4];
                #pragma unroll
                for (int r = 0; r < 4; ++r) {
                    float g = gelu_f(acc[mi][n][r]);
                    pv[r] = fmaxf(g, __shfl_xor(g, 8));
                }
                if (hi8 == 0) {
                    uint2 pk;
                    pk.x = cvt_pk_bf16(pv[0], pv[1]);
                    pk.y = cvt_pk_bf16(pv[2], pv[3]);
                    *(uint2*)&hpT[seg8*S2 + (lp+1)*128 + co0] = pk;
                }
            }
        }
    }
    __syncthreads();

    // conv3 GEMM: M=256, N=80, K=384; bias in acc; gelu + mean; bf16 feat output
    {
        f32x4 bias[2];
        #pragma unroll
        for (int mi = 0; mi < 2; ++mi) {
            float4 bv = *(const float4*)(b3 + (wave*2 + mi)*16 + gL*4);
            bias[mi] = (f32x4){bv.x, bv.y, bv.z, bv.w};
        }
        f32x4 acc[2][5];
        #pragma unroll
        for (int mi = 0; mi < 2; ++mi)
            #pragma unroll
            for (int n = 0; n < 5; ++n) acc[mi][n] = bias[mi];

        const unsigned short* hpbase = &hpT[seg8*S2 + hi8*128 + gL*8];
        #pragma unroll
        for (int q = 0; q < 4; ++q) {
            short8 br[11];
            #pragma unroll
            for (int r = 0; r < 11; ++r)
                br[r] = *(const short8*)(hpbase + r*128 + q*32);
            #pragma unroll
            for (int k = 0; k < 3; ++k) {
                int kt = k*4 + q;
                short8 a0 = *(const short8*)(A3p + (((kt*16 + wave*2 + 0)*64 + lane) << 3));
                short8 a1 = *(const short8*)(A3p + (((kt*16 + wave*2 + 1)*64 + lane) << 3));
                #pragma unroll
                for (int n = 0; n < 5; ++n) {
                    acc[0][n] = __builtin_amdgcn_mfma_f32_16x16x32_bf16(a0, br[2*n+k], acc[0][n], 0, 0, 0);
                    acc[1][n] = __builtin_amdgcn_mfma_f32_16x16x32_bf16(a1, br[2*n+k], acc[1][n], 0, 0, 0);
                }
            }
        }
        int seg = seg0 + seg8;
        int bI = seg / (C_*P_);
        int rem = seg % (C_*P_);
        int c = rem / P_, p = rem % P_;
        unsigned short* frow = feat + (((size_t)(bI*P_ + p)*C_ + c) << 8);
        #pragma unroll
        for (int mi = 0; mi < 2; ++mi) {
            int co0 = (wave*2 + mi)*16 + gL*4;
            float sum[4] = {0.f, 0.f, 0.f, 0.f};
            #pragma unroll
            for (int n = 0; n < 5; ++n)
                #pragma unroll
                for (int r = 0; r < 4; ++r)
                    sum[r] += gelu_f(acc[mi][n][r]);
            #pragma unroll
            for (int r = 0; r < 4; ++r)
                sum[r] += __shfl_xor(sum[r], 8);
            if (hi8 == 0) {
                uint2 o;
                o.x = cvt_pk_bf16(sum[0]*0.1f, sum[1]*0.1f);
                o.y = cvt_pk_bf16(sum[2]*0.1f, sum[3]*0.1f);
                *(uint2*)(frow + co0) = o;
            }
        }
    }
}

// ---------------- kernel 2: fused mix + gelu + LN + proj (MFMA) ----------------
__global__ __launch_bounds__(512, 2) void mix_proj_kernel(
    const unsigned short* __restrict__ feat,
    const unsigned short* __restrict__ mixA, const float* __restrict__ bmixp,
    const float* __restrict__ lnwp, const float* __restrict__ lnbp,
    const unsigned short* __restrict__ projA, const float* __restrict__ proj_b,
    float* __restrict__ out)
{
    __shared__ __align__(16) unsigned short ulds[256*FT_STRIDE];
    unsigned short* fT = ulds;
    unsigned short* mT = ulds;

    const int t = threadIdx.x;
    const int wave = t >> 6, lane = t & 63;
    const int sL = lane & 15, gL = lane >> 4;
    const int n2 = blockIdx.x;
    const int b = n2 / P_, p = n2 % P_;

    // stage fT[d][c] from bf16 feat (pure copy; pairs of d per u32)
    const unsigned* fbase32 = (const unsigned*)(feat + (size_t)n2 * C_ * 256);
    for (int idx = t; idx < 129*128; idx += 512) {
        int c = idx >> 7, q = idx & 127;
        unsigned v = fbase32[idx];
        int d0 = q * 2;
        fT[d0*FT_STRIDE + c]     = (unsigned short)(v & 0xFFFFu);
        fT[(d0+1)*FT_STRIDE + c] = (unsigned short)(v >> 16);
    }
    for (int idx = t; idx < 256*31; idx += 512) {
        int d = idx / 31, c = 129 + idx % 31;
        fT[d*FT_STRIDE + c] = 0;
    }
    __syncthreads();

    // mix GEMM: bias preloaded into accumulators (zero rows for o>=129)
    f32x4 acc[9][2];
    #pragma unroll
    for (int mt = 0; mt < 9; ++mt) {
        float4 bv = *(const float4*)(bmixp + mt*16 + gL*4);
        f32x4 bi = (f32x4){bv.x, bv.y, bv.z, bv.w};
        acc[mt][0] = bi;
        acc[mt][1] = bi;
    }

    #pragma unroll
    for (int kt = 0; kt < 5; ++kt) {
        short8 bb[2];
        #pragma unroll
        for (int nt = 0; nt < 2; ++nt) {
            int d = (wave*2 + nt)*16 + sL;
            bb[nt] = *(const short8*)&fT[d*FT_STRIDE + kt*32 + gL*8];
        }
        #pragma unroll
        for (int mt = 0; mt < 9; ++mt) {
            short8 a = *(const short8*)(mixA + (((kt*9 + mt)*64 + lane) << 3));
            #pragma unroll
            for (int nt = 0; nt < 2; ++nt)
                acc[mt][nt] = __builtin_amdgcn_mfma_f32_16x16x32_bf16(a, bb[nt], acc[mt][nt], 0, 0, 0);
        }
    }

    // gelu + LN stats (acc=0 for o>=129 -> gelu(0)=0 exactly, no mask needed)
    float sum[2] = {0.f, 0.f}, sq[2] = {0.f, 0.f};
    #pragma unroll
    for (int mt = 0; mt < 9; ++mt) {
        #pragma unroll
        for (int nt = 0; nt < 2; ++nt) {
            #pragma unroll
            for (int r = 0; r < 4; ++r) {
                float g = gelu_f(acc[mt][nt][r]);
                acc[mt][nt][r] = g;
                sum[nt] += g;
                sq[nt]  += g*g;
            }
        }
    }
    float mu[2], rs[2];
    #pragma unroll
    for (int nt = 0; nt < 2; ++nt) {
        float s = sum[nt], q = sq[nt];
        s += __shfl_xor(s, 16); q += __shfl_xor(q, 16);
        s += __shfl_xor(s, 32); q += __shfl_xor(q, 32);
        mu[nt] = s * (1.f/129.f);
        float var = q * (1.f/129.f) - mu[nt]*mu[nt];
        rs[nt] = rsqrtf(var + 1e-5f);
    }

    __syncthreads();

    #pragma unroll
    for (int mt = 0; mt < 9; ++mt) {
        float4 lw = *(const float4*)(lnwp + mt*16 + gL*4);
        float4 lb = *(const float4*)(lnbp + mt*16 + gL*4);
        float lwr[4] = {lw.x, lw.y, lw.z, lw.w};
        float lbr[4] = {lb.x, lb.y, lb.z, lb.w};
        #pragma unroll
        for (int nt = 0; nt < 2; ++nt) {
            int d = (wave*2 + nt)*16 + sL;
            #pragma unroll
            for (int r = 0; r < 4; ++r) {
                int o = mt*16 + gL*4 + r;
                float y = (acc[mt][nt][r] - mu[nt]) * rs[nt] * lwr[r] + lbr[r];
                mT[o*MT_STRIDE + d] = f2bf(y);
            }
        }
    }
    __syncthreads();

    f32x4 pacc[2][9];
    #pragma unroll
    for (int mi = 0; mi < 2; ++mi)
        #pragma unroll
        for (int nt = 0; nt < 9; ++nt) pacc[mi][nt] = (f32x4){0.f,0.f,0.f,0.f};

    #pragma unroll
    for (int kt = 0; kt < 8; ++kt) {
        short8 a[2];
        #pragma unroll
        for (int mi = 0; mi < 2; ++mi)
            a[mi] = *(const short8*)(projA + (((kt*16 + wave*2 + mi)*64 + lane) << 3));
        #pragma unroll
        for (int nt = 0; nt < 9; ++nt) {
            short8 bb = *(const short8*)&mT[(nt*16 + sL)*MT_STRIDE + kt*32 + gL*8];
            #pragma unroll
            for (int mi = 0; mi < 2; ++mi)
                pacc[mi][nt] = __builtin_amdgcn_mfma_f32_16x16x32_bf16(a[mi], bb, pacc[mi][nt], 0, 0, 0);
        }
    }

    #pragma unroll
    for (int mi = 0; mi < 2; ++mi) {
        int e0 = (wave*2 + mi)*16 + gL*4;
        float4 pb4 = *(const float4*)(proj_b + e0);
        #pragma unroll
        for (int nt = 0; nt < 9; ++nt) {
            int c = nt*16 + sL;
            if (c < 129) {
                float4 o4;
                o4.x = pacc[mi][nt][0] + pb4.x;
                o4.y = pacc[mi][nt][1] + pb4.y;
                o4.z = pacc[mi][nt][2] + pb4.z;
                o4.w = pacc[mi][nt][3] + pb4.w;
                *(float4*)&out[(((size_t)(b*C_ + c)*P_) + p)*256 + e0] = o4;
            }
        }
    }
}

extern "C" void kernel_launch(void* const* d_in, const int* in_sizes, int n_in,
                              void* d_out, int out_size, void* d_ws, size_t ws_size,
                              hipStream_t stream) {
    (void)in_sizes; (void)n_in; (void)out_size; (void)ws_size;
    const float* x    = (const float*)d_in[0];
    const float* w1   = (const float*)d_in[1];
    const float* b1   = (const float*)d_in[2];
    const float* w2   = (const float*)d_in[3];
    const float* b2   = (const float*)d_in[4];
    const float* w3   = (const float*)d_in[5];
    const float* b3   = (const float*)d_in[6];
    const float* mixw = (const float*)d_in[7];
    const float* mixb = (const float*)d_in[8];
    const float* lnw  = (const float*)d_in[9];
    const float* lnb  = (const float*)d_in[10];
    const float* pw   = (const float*)d_in[11];
    const float* pb   = (const float*)d_in[12];
    float* out = (float*)d_out;
    float* ws  = (float*)d_ws;

    unsigned short* feat = (unsigned short*)ws;              // 63984*256 bf16 (32.7 MB)
    unsigned short* A2p  = (unsigned short*)(ws + 16379904); // 24576 u16
    unsigned short* A3p  = A2p + 24576;                      // 98304 u16
    unsigned short* mixA = A3p + 98304;                      // 23040 u16
    unsigned short* projA = mixA + 23040;                    // 65536 u16
    float* bmixp = (float*)(projA + 65536);                  // 144
    float* lnwp  = bmixp + 144;                              // 144
    float* lnbp  = lnwp + 144;                               // 144

    prep_kernel<<<256, 256, 0, stream>>>(w2, w3, mixw, pw, mixb, lnw, lnb,
                                         A2p, A3p, mixA, projA, bmixp, lnwp, lnbp);
    conv_mfma_kernel<<<NWG, 512, 0, stream>>>(x, w1, b1, A2p, b2, A3p, b3, feat);
    mix_proj_kernel<<<N2, 512, 0, stream>>>(feat, mixA, bmixp, lnwp, lnbp, projA, pb, out);
}